// Round 1
// baseline (234.503 us; speedup 1.0000x reference)
//
#include <hip/hip_runtime.h>
#include <math.h>

#define BATCH    65536
#define FEAT     512
#define NCLASS   16
#define LAMDA    1.0f
#define LAMDA1   10.0f
#define SCALE    1.0f
#define EPS      1e-9f

// ---------------------------------------------------------------------------
// Kernel 1: center loss partial sums.
// sum over all (b,d) of (x[b,d] - centers[y[b], d])^2, accumulated into ws[0].
// float4 vectorized: NV = BATCH * FEAT / 4 = 8,388,608 float4 elements.
// ---------------------------------------------------------------------------
__global__ __launch_bounds__(256) void center_loss_kernel(
    const float4* __restrict__ x,        // [BATCH * FEAT/4]
    const int*    __restrict__ y,        // [BATCH]
    const float4* __restrict__ centers,  // [NCLASS * FEAT/4]
    float*        __restrict__ accum)    // [1], pre-zeroed
{
    const int NV = BATCH * (FEAT / 4);
    const int stride = gridDim.x * blockDim.x;
    float sum = 0.0f;
    for (int i = blockIdx.x * blockDim.x + threadIdx.x; i < NV; i += stride) {
        float4 xv = x[i];
        int b  = i >> 7;        // FEAT/4 = 128 float4 per row
        int d4 = i & 127;
        int cls = y[b];
        float4 cv = centers[cls * (FEAT / 4) + d4];
        float e0 = xv.x - cv.x;
        float e1 = xv.y - cv.y;
        float e2 = xv.z - cv.z;
        float e3 = xv.w - cv.w;
        sum += e0 * e0 + e1 * e1 + e2 * e2 + e3 * e3;
    }

    // wave (64-lane) shuffle reduction
    #pragma unroll
    for (int off = 32; off > 0; off >>= 1)
        sum += __shfl_down(sum, off, 64);

    __shared__ float wsum[4];
    int lane = threadIdx.x & 63;
    int wid  = threadIdx.x >> 6;
    if (lane == 0) wsum[wid] = sum;
    __syncthreads();
    if (threadIdx.x == 0) {
        float s = wsum[0] + wsum[1] + wsum[2] + wsum[3];
        atomicAdd(accum, s);
    }
}

// ---------------------------------------------------------------------------
// Kernel 2 (single block, 256 threads): pairwise cosine over centers + final
// combine.  Thread t = (j = t>>4, k = t&15) computes gram[j][k].
// LDS centers padded to stride 513 (513 % 32 == 1) -> conflict-free dot loop.
// ---------------------------------------------------------------------------
__global__ __launch_bounds__(256) void finalize_kernel(
    const float* __restrict__ centers,   // [NCLASS * FEAT]
    const float* __restrict__ accum,     // [1] = sum of squared diffs
    float*       __restrict__ out)       // [1]
{
    __shared__ float c[NCLASS][FEAT + 1];
    __shared__ float gram[NCLASS][NCLASS];

    // coalesced staging of the 16x512 center matrix
    for (int i = threadIdx.x; i < NCLASS * FEAT; i += 256) {
        c[i >> 9][i & 511] = centers[i];
    }
    __syncthreads();

    int j = threadIdx.x >> 4;
    int k = threadIdx.x & 15;
    float dot = 0.0f;
    #pragma unroll 8
    for (int i = 0; i < FEAT; ++i)
        dot += c[j][i] * c[k][i];
    gram[j][k] = dot;
    __syncthreads();

    if (threadIdx.x == 0) {
        float item1 = 0.0f;
        for (int jj = 0; jj < NCLASS; ++jj) {
            float nj = sqrtf(gram[jj][jj]);
            for (int kk = jj + 1; kk < NCLASS; ++kk) {
                float nk = sqrtf(gram[kk][kk]);
                float cosv = gram[jj][kk] / (nj * nk + EPS);
                item1 += cosv + 1.0f;
            }
        }
        float loss_center = 0.5f * accum[0] * (SCALE / (float)BATCH);
        out[0] = LAMDA * (loss_center + LAMDA1 * item1);
    }
}

extern "C" void kernel_launch(void* const* d_in, const int* in_sizes, int n_in,
                              void* d_out, int out_size, void* d_ws, size_t ws_size,
                              hipStream_t stream) {
    const float* x       = (const float*)d_in[0];   // [BATCH, FEAT]
    const int*   y       = (const int*)d_in[1];     // [BATCH]
    const float* centers = (const float*)d_in[2];   // [NCLASS, FEAT]
    float* out   = (float*)d_out;
    float* accum = (float*)d_ws;

    hipMemsetAsync(accum, 0, sizeof(float), stream);

    dim3 grid(4096), block(256);
    center_loss_kernel<<<grid, block, 0, stream>>>(
        (const float4*)x, y, (const float4*)centers, accum);

    finalize_kernel<<<1, 256, 0, stream>>>(centers, accum, out);
}